// Round 6
// baseline (9567.963 us; speedup 1.0000x reference)
//
#include <hip/hip_runtime.h>
#include <stdint.h>
#include <math.h>

// ---------------------------------------------------------------------------
// QuantumDiffusionDreamer — round 6: r5 + operand-swapped MFMA epilogue.
// mfma(Wt-frag, x-frag) -> D = C^T-fragments: each lane holds 4 consecutive
// C-columns at fixed C-row -> pack 4 bf16 -> one 8B store per (u,v)
// (16 dwordx2 stores/thread instead of 64 scalar shorts). Bias via float4.
// Everything else identical to r5 (measured 9.42 ms).
// PRNG: JAX threefry2x32 partitionable (verified r1-r5). x stays fp32.
// ---------------------------------------------------------------------------

typedef __bf16 bf16x8 __attribute__((ext_vector_type(8)));
typedef float floatx4 __attribute__((ext_vector_type(4)));
typedef unsigned int uintx2 __attribute__((ext_vector_type(2)));

__host__ __device__ inline void tf2x32(uint32_t k0, uint32_t k1,
                                       uint32_t x0, uint32_t x1,
                                       uint32_t& o0, uint32_t& o1) {
  uint32_t ks2 = k0 ^ k1 ^ 0x1BD11BDAu;
#define TF_R(r) { x0 += x1; x1 = (x1 << (r)) | (x1 >> (32 - (r))); x1 ^= x0; }
  x0 += k0; x1 += k1;
  TF_R(13) TF_R(15) TF_R(26) TF_R(6)
  x0 += k1;  x1 += ks2 + 1u;
  TF_R(17) TF_R(29) TF_R(16) TF_R(24)
  x0 += ks2; x1 += k0 + 2u;
  TF_R(13) TF_R(15) TF_R(26) TF_R(6)
  x0 += k0;  x1 += k1 + 3u;
  TF_R(17) TF_R(29) TF_R(16) TF_R(24)
  x0 += k1;  x1 += ks2 + 4u;
  TF_R(13) TF_R(15) TF_R(26) TF_R(6)
  x0 += ks2; x1 += k0 + 5u;
#undef TF_R
  o0 = x0; o1 = x1;
}

__device__ inline float erfinv_f32(float x) {
  float w = -log1pf(-x * x);
  float p;
  if (w < 5.0f) {
    w = w - 2.5f;
    p = 2.81022636e-08f;
    p = fmaf(p, w, 3.43273939e-07f);
    p = fmaf(p, w, -3.5233877e-06f);
    p = fmaf(p, w, -4.39150654e-06f);
    p = fmaf(p, w, 0.00021858087f);
    p = fmaf(p, w, -0.00125372503f);
    p = fmaf(p, w, -0.00417768164f);
    p = fmaf(p, w, 0.246640727f);
    p = fmaf(p, w, 1.50140941f);
  } else {
    w = sqrtf(w) - 3.0f;
    p = -0.000200214257f;
    p = fmaf(p, w, 0.000100950558f);
    p = fmaf(p, w, 0.00134934322f);
    p = fmaf(p, w, -0.00367342844f);
    p = fmaf(p, w, 0.00573950773f);
    p = fmaf(p, w, -0.0076224613f);
    p = fmaf(p, w, 0.00943887047f);
    p = fmaf(p, w, 1.00167406f);
    p = fmaf(p, w, 2.83297682f);
  }
  return p * x;
}

__device__ inline float tf_normal(uint32_t k0, uint32_t k1, uint32_t i) {
  uint32_t o0, o1;
  tf2x32(k0, k1, 0u, i, o0, o1);
  uint32_t bits = o0 ^ o1;  // partitionable random_bits path
  float f = __uint_as_float(0x3F800000u | (bits >> 9)) - 1.0f;  // [0,1)
  float u = f * 2.0f + (-0.99999994f);
  u = fmaxf(-0.99999994f, u);
  return 1.41421356f * erfinv_f32(u);
}

__device__ inline unsigned short f2bf(float f) {
  uint32_t u = __float_as_uint(f);
  u += 0x7FFFu + ((u >> 16) & 1u);   // round-to-nearest-even
  return (unsigned short)(u >> 16);
}
__device__ inline float bf2f(unsigned short h) {
  return __uint_as_float(((uint32_t)h) << 16);
}
// pack 4 fp32 -> 4 bf16 (RNE) in 8 bytes
__device__ inline uintx2 pack4bf(float a, float b, float c, float d) {
  uintx2 r;
  r.x = (uint32_t)f2bf(a) | ((uint32_t)f2bf(b) << 16);
  r.y = (uint32_t)f2bf(c) | ((uint32_t)f2bf(d) << 16);
  return r;
}

// ---------------------------------------------------------------------------
// Weight transpose + bf16 convert: Wt[n][k] = bf16(W[k][n]);  W is [K,N] fp32.
// ---------------------------------------------------------------------------
__global__ __launch_bounds__(256)
void transpose_bf16_kernel(const float* __restrict__ W,
                           unsigned short* __restrict__ Wt, int K, int N) {
  __shared__ float tile[32][33];
  int kb = blockIdx.x * 32, nb = blockIdx.y * 32;
  int tx = threadIdx.x & 31, ty = threadIdx.x >> 5;
#pragma unroll
  for (int i = 0; i < 32; i += 8)
    tile[ty + i][tx] = W[(size_t)(kb + ty + i) * N + nb + tx];
  __syncthreads();
#pragma unroll
  for (int i = 0; i < 32; i += 8)
    Wt[(size_t)(nb + ty + i) * K + kb + tx] = f2bf(tile[tx][ty + i]);
}

// ---------------------------------------------------------------------------
// Double-buffered MFMA core, OPERAND-SWAPPED: acc[v][u] = Wt-frag x x-frag
// -> lane (fm,quad) holds C[row0+wr*64+u*16+fm][col0+wc*64+v*16+quad*4 + r],
// r=0..3 consecutive columns -> 8B-packable stores in the epilogue.
// 128x128 tile, BK=32, 4 waves, 16x16x32 bf16 MFMA, global_load_lds(16B),
// raw `s_waitcnt vmcnt(4); s_barrier` keeps next tile's loads in flight.
// ---------------------------------------------------------------------------
__device__ __forceinline__ void gemm_core_db(
    const unsigned short* __restrict__ A0, const unsigned short* __restrict__ A1,
    int lda0, int lda1, int K0, int Ktot,
    const unsigned short* __restrict__ Bt,
    int row0, int col0,
    unsigned short (*As)[128 * 32], unsigned short (*Bs)[128 * 32],
    floatx4 (&acc)[4][4]) {
  const int tid = threadIdx.x;
  const int wave = tid >> 6, lane = tid & 63;
  const int wr = wave >> 1, wc = wave & 1;
  const int lrow = lane >> 2;       // 0..15
  const int lk = (lane & 3) * 8;    // 0,8,16,24
  const int fm = lane & 15, quad = lane >> 4;

  auto issue = [&](int kt, int buf) {
    const int k0 = kt * 32;
    const unsigned short* Ap; int kOff, lda;
    if (k0 < K0) { Ap = A0; kOff = k0; lda = lda0; }
    else         { Ap = A1; kOff = k0 - K0; lda = lda1; }
#pragma unroll
    for (int r = 0; r < 2; r++) {
      int srow = r * 64 + wave * 16 + lrow;   // lane-contiguous LDS order
      __builtin_amdgcn_global_load_lds(
          (const __attribute__((address_space(1))) uint32_t*)
              (Ap + (size_t)(row0 + srow) * lda + kOff + lk),
          (__attribute__((address_space(3))) uint32_t*)(&As[buf][srow * 32 + lk]),
          16, 0, 0);
      __builtin_amdgcn_global_load_lds(
          (const __attribute__((address_space(1))) uint32_t*)
              (Bt + (size_t)(col0 + srow) * Ktot + k0 + lk),
          (__attribute__((address_space(3))) uint32_t*)(&Bs[buf][srow * 32 + lk]),
          16, 0, 0);
    }
  };

  const int nk = Ktot >> 5;
  issue(0, 0);
  for (int k = 0; k < nk; k++) {
    const int cur = k & 1;
    if (k + 1 < nk) {
      issue(k + 1, cur ^ 1);
      asm volatile("s_waitcnt vmcnt(4)\ns_barrier" ::: "memory");
    } else {
      asm volatile("s_waitcnt vmcnt(0)\ns_barrier" ::: "memory");
    }
    bf16x8 wfrag[4], xfrag[4];
#pragma unroll
    for (int v = 0; v < 4; v++)
      wfrag[v] = *(const bf16x8*)(&Bs[cur][(wc * 64 + v * 16 + fm) * 32 + quad * 8]);
#pragma unroll
    for (int u = 0; u < 4; u++)
      xfrag[u] = *(const bf16x8*)(&As[cur][(wr * 64 + u * 16 + fm) * 32 + quad * 8]);
#pragma unroll
    for (int v = 0; v < 4; v++)
#pragma unroll
      for (int u = 0; u < 4; u++)
        acc[v][u] = __builtin_amdgcn_mfma_f32_16x16x32_bf16(wfrag[v], xfrag[u],
                                                            acc[v][u], 0, 0, 0);
    asm volatile("s_barrier" ::: "memory");
  }
}

// XCD-aware swizzle: gy is always 64 (M=8192). by = id%64, bx = id/64 makes
// all col-blocks of one row-block share id%8 -> same XCD (performance-only).
__device__ __forceinline__ void swizzled_block(int& row0, int& col0) {
  int id = blockIdx.x + gridDim.x * blockIdx.y;
  row0 = (id & 63) << 7;
  col0 = (id >> 6) << 7;
}

// Generic GEMM. ACT: 0 none, 1 relu, 2 tanh, 3 gelu(exact),
// 4 = split epilogue: cols < nsplit -> relu+bias0 -> C0; else tanh+bias1 -> C1
// (nsplit multiple of 128 -> block-uniform side select).
template<int ACT>
__global__ __launch_bounds__(256)
void mfma_gemm(const unsigned short* __restrict__ A0,
               const unsigned short* __restrict__ A1,
               int lda0, int lda1, int K0, int Ktot,
               const unsigned short* __restrict__ Bt,
               const float* __restrict__ bias0,
               const float* __restrict__ bias1, int nsplit,
               unsigned short* __restrict__ C0,
               unsigned short* __restrict__ C1, int ldc) {
  __shared__ unsigned short As[2][128 * 32];
  __shared__ unsigned short Bs[2][128 * 32];
  int row0, col0;
  swizzled_block(row0, col0);
  floatx4 acc[4][4];
#pragma unroll
  for (int v = 0; v < 4; v++)
#pragma unroll
    for (int u = 0; u < 4; u++) acc[v][u] = (floatx4){0.f, 0.f, 0.f, 0.f};
  gemm_core_db(A0, A1, lda0, lda1, K0, Ktot, Bt, row0, col0, As, Bs, acc);

  const int lane = threadIdx.x & 63, wave = threadIdx.x >> 6;
  const int wr = wave >> 1, wc = wave & 1;
  const int fm = lane & 15, quad = lane >> 4;
  const bool side = (ACT == 4) && (col0 >= nsplit);
  const float* bias = side ? bias1 : bias0;
  unsigned short* C = side ? C1 : C0;
  const int cbase = col0 - (side ? nsplit : 0) + wc * 64 + quad * 4;
#pragma unroll
  for (int v = 0; v < 4; v++) {
    int colb = cbase + v * 16;
    floatx4 bv = *(const floatx4*)(bias + colb);
#pragma unroll
    for (int u = 0; u < 4; u++) {
      int row = row0 + wr * 64 + u * 16 + fm;
      float t[4];
#pragma unroll
      for (int r = 0; r < 4; r++) {
        float val = acc[v][u][r] + bv[r];
        if (ACT == 1) val = fmaxf(val, 0.0f);
        if (ACT == 2) val = tanhf(val);
        if (ACT == 3) val = 0.5f * val * (1.0f + erff(val * 0.70710678118654752f));
        if (ACT == 4) val = side ? tanhf(val) : fmaxf(val, 0.0f);
        t[r] = val;
      }
      *(uintx2*)(C + (size_t)row * ldc + colb) = pack4bf(t[0], t[1], t[2], t[3]);
    }
  }
}

// z-batched pair of independent GEMMs (same shapes). No activation.
__global__ __launch_bounds__(256)
void mfma_gemm_pair(const unsigned short* __restrict__ Aa,
                    const unsigned short* __restrict__ Ab,
                    const unsigned short* __restrict__ Bta,
                    const unsigned short* __restrict__ Btb,
                    const float* __restrict__ biasa,
                    const float* __restrict__ biasb,
                    unsigned short* __restrict__ Ca,
                    unsigned short* __restrict__ Cb,
                    int Ktot, int ldc) {
  __shared__ unsigned short As[2][128 * 32];
  __shared__ unsigned short Bs[2][128 * 32];
  const int z = blockIdx.z;
  const unsigned short* A = z ? Ab : Aa;
  const unsigned short* Bt = z ? Btb : Bta;
  const float* bias = z ? biasb : biasa;
  unsigned short* C = z ? Cb : Ca;
  int row0, col0;
  swizzled_block(row0, col0);
  floatx4 acc[4][4];
#pragma unroll
  for (int v = 0; v < 4; v++)
#pragma unroll
    for (int u = 0; u < 4; u++) acc[v][u] = (floatx4){0.f, 0.f, 0.f, 0.f};
  gemm_core_db(A, A, Ktot, Ktot, Ktot, Ktot, Bt, row0, col0, As, Bs, acc);

  const int lane = threadIdx.x & 63, wave = threadIdx.x >> 6;
  const int wr = wave >> 1, wc = wave & 1;
  const int fm = lane & 15, quad = lane >> 4;
  const int cbase = col0 + wc * 64 + quad * 4;
#pragma unroll
  for (int v = 0; v < 4; v++) {
    int colb = cbase + v * 16;
    floatx4 bv = *(const floatx4*)(bias + colb);
#pragma unroll
    for (int u = 0; u < 4; u++) {
      int row = row0 + wr * 64 + u * 16 + fm;
      *(uintx2*)(C + (size_t)row * ldc + colb) =
          pack4bf(acc[v][u][0] + bv[0], acc[v][u][1] + bv[1],
                  acc[v][u][2] + bv[2], acc[v][u][3] + bv[3]);
    }
  }
}

__global__ void init_normal_kernel(float* __restrict__ x,
                                   unsigned short* __restrict__ xbf,
                                   uint32_t k0, uint32_t k1, int n) {
  int i = blockIdx.x * blockDim.x + threadIdx.x;
  if (i >= n) return;
  float v = tf_normal(k0, k1, (uint32_t)i);
  x[i] = v;
  xbf[i] = f2bf(v);
}

__global__ void update_kernel(float* __restrict__ x,
                              unsigned short* __restrict__ xbf,
                              const unsigned short* __restrict__ d0,
                              const unsigned short* __restrict__ d1,
                              const unsigned short* __restrict__ itf,
                              const float* __restrict__ a_amp,
                              const float* __restrict__ b_amp,
                              const float* __restrict__ ph,
                              float coh, float c1, float sqrt_alpha,
                              float sigma, int add_noise,
                              uint32_t k0, uint32_t k1, int n) {
  int i = blockIdx.x * blockDim.x + threadIdx.x;
  if (i >= n) return;
  float aa = a_amp[0], bb = b_amp[0], pc = ph[0];
  float a2 = aa * aa, b2 = bb * bb, s = a2 + b2;
  float p0 = a2 / s, p1 = b2 / s;
  float qi = 2.0f * sqrtf(p0 * p1) * pc * coh;
  float den = sqrtf(p0) * bf2f(d0[i]) + sqrtf(p1) * bf2f(d1[i])
            + qi * bf2f(itf[i]);
  float xn = (x[i] - c1 * den) / sqrt_alpha;
  if (add_noise) {
    float nz = tf_normal(k0, k1, (uint32_t)i);
    xn += (sigma + 0.1f * fabsf(qi)) * nz;
  }
  x[i] = xn;
  xbf[i] = f2bf(xn);
}

__global__ void final_kernel(const float* __restrict__ x,
                             const float* __restrict__ real,
                             float* __restrict__ out,
                             const float* __restrict__ a_amp,
                             const float* __restrict__ b_amp,
                             uint32_t k0, uint32_t k1, int n) {
  int i = blockIdx.x * blockDim.x + threadIdx.x;
  if (i >= n) return;
  float aa = a_amp[0], bb = b_amp[0];
  float a2 = aa * aa, b2 = bb * bb;
  float p0 = a2 / (a2 + b2);
  uint32_t o0, o1;
  tf2x32(k0, k1, 0u, 0u, o0, o1);
  uint32_t bits = o0 ^ o1;
  float u = __uint_as_float(0x3F800000u | (bits >> 9)) - 1.0f;
  float xv = x[i];
  out[i] = (u < p0) ? (0.7f * xv + 0.3f * real[i]) : xv;
}

extern "C" void kernel_launch(void* const* d_in, const int* in_sizes, int n_in,
                              void* d_out, int out_size, void* d_ws,
                              size_t ws_size, hipStream_t stream) {
  const float* real = (const float*)d_in[0];
  const float* Wq  = (const float*)d_in[2];
  const float* bq  = (const float*)d_in[3];
  const float* W01 = (const float*)d_in[4];
  const float* b01 = (const float*)d_in[5];
  const float* W02 = (const float*)d_in[6];
  const float* b02 = (const float*)d_in[7];
  const float* W11 = (const float*)d_in[8];
  const float* b11 = (const float*)d_in[9];
  const float* W12 = (const float*)d_in[10];
  const float* b12 = (const float*)d_in[11];
  const float* Wi1 = (const float*)d_in[12];
  const float* bi1 = (const float*)d_in[13];
  const float* Wi2 = (const float*)d_in[14];
  const float* bi2 = (const float*)d_in[15];
  const float* a_amp = (const float*)d_in[16];
  const float* b_amp = (const float*)d_in[17];
  const float* ph    = (const float*)d_in[18];

  const int Nn = 8192, F = 512, H = 1024;
  const int nElem = Nn * F;  // 4,194,304
  const int NSPLIT_OFF = 1 << 30;

  // workspace layout
  char* ws = (char*)d_ws;
  float* x = (float*)ws;                                   ws += (size_t)nElem * 4;
  unsigned short* xbf = (unsigned short*)ws;               ws += (size_t)nElem * 2;
  unsigned short* qf  = (unsigned short*)ws;               ws += (size_t)Nn * H * 2;
  unsigned short* h0  = (unsigned short*)ws;               ws += (size_t)Nn * H * 2;
  unsigned short* h1  = (unsigned short*)ws;               ws += (size_t)Nn * H * 2;
  unsigned short* d0  = (unsigned short*)ws;               ws += (size_t)nElem * 2;
  unsigned short* d1  = (unsigned short*)ws;               ws += (size_t)nElem * 2;
  unsigned short* itf = (unsigned short*)ws;               ws += (size_t)nElem * 2;
  unsigned short* Wq_t  = (unsigned short*)ws;             ws += (size_t)F * H * 2;
  unsigned short* WA_t  = (unsigned short*)ws;             ws += (size_t)(2 * H) * H * 2; // [W01_t ; W11_t]
  unsigned short* W02_t = (unsigned short*)ws;             ws += (size_t)H * F * 2;
  unsigned short* W12_t = (unsigned short*)ws;             ws += (size_t)H * F * 2;
  unsigned short* Wi1_t = (unsigned short*)ws;             ws += (size_t)(2 * F) * H * 2;
  unsigned short* Wi2_t = (unsigned short*)ws;             ws += (size_t)H * F * 2;

  dim3 tb(256);
  transpose_bf16_kernel<<<dim3(F / 32, H / 32), tb, 0, stream>>>(Wq, Wq_t, F, H);
  transpose_bf16_kernel<<<dim3(H / 32, H / 32), tb, 0, stream>>>(W01, WA_t, H, H);
  transpose_bf16_kernel<<<dim3(H / 32, H / 32), tb, 0, stream>>>(W11, WA_t + (size_t)H * H, H, H);
  transpose_bf16_kernel<<<dim3(H / 32, F / 32), tb, 0, stream>>>(W02, W02_t, H, F);
  transpose_bf16_kernel<<<dim3(H / 32, F / 32), tb, 0, stream>>>(W12, W12_t, H, F);
  transpose_bf16_kernel<<<dim3(2 * F / 32, H / 32), tb, 0, stream>>>(Wi1, Wi1_t, 2 * F, H);
  transpose_bf16_kernel<<<dim3(H / 32, F / 32), tb, 0, stream>>>(Wi2, Wi2_t, H, F);

  uint32_t kx0, kx1; tf2x32(0u, 1u, 0u, 10000u, kx0, kx1);
  init_normal_kernel<<<(nElem + 255) / 256, 256, 0, stream>>>(x, xbf, kx0, kx1, nElem);

  float sched[100];
  for (int i = 0; i < 100; i++)
    sched[i] = (float)(1e-4 + (0.02 - 1e-4) * (double)i / 99.0);
  const float decay = expf(-0.1f);
  float coh = 1.0f;

  dim3 blk(256);
  dim3 g1(H / 128, 64);            // 512 blocks
  dim3 g2(2 * H / 128, 64);        // 1024 blocks
  dim3 g45(F / 128, 64, 2);        // 512 blocks
  dim3 g6(H / 128, 64);            // 512 blocks
  dim3 g7(F / 128, 64);            // 256 blocks

  for (int j = 0; j < 50; j++) {
    int t = 49 - j;
    // G1: qf = relu(x @ Wq + bq)
    mfma_gemm<1><<<g1, blk, 0, stream>>>(xbf, xbf, F, F, F, F, Wq_t,
                                         bq, nullptr, NSPLIT_OFF, qf, nullptr, H);
    // G2 merged: h0 = relu(qf@W01+b01), h1 = tanh(qf@W11+b11) in one N=2048 GEMM
    mfma_gemm<4><<<g2, blk, 0, stream>>>(qf, qf, H, H, H, H, WA_t,
                                         b01, b11, H, h0, h1, H);
    // G4/G5 z-batched: d0 = h0@W02+b02 ; d1 = h1@W12+b12
    mfma_gemm_pair<<<g45, blk, 0, stream>>>(h0, h1, W02_t, W12_t, b02, b12,
                                            d0, d1, H, F);
    // G6: qf(reused) = gelu([d0|d1] @ Wi1 + bi1)
    mfma_gemm<3><<<g6, blk, 0, stream>>>(d0, d1, F, F, F, 2 * F, Wi1_t,
                                         bi1, nullptr, NSPLIT_OFF, qf, nullptr, H);
    // G7: itf = qf @ Wi2 + bi2
    mfma_gemm<0><<<g7, blk, 0, stream>>>(qf, qf, H, H, H, H, Wi2_t,
                                         bi2, nullptr, NSPLIT_OFF, itf, nullptr, F);

    float schedt = sched[t];
    float alphaf = fmaxf(1.0f - schedt, 1e-8f);
    float one_m_alpha = 1.0f - alphaf;
    float sqrt_1ma = sqrtf(fmaxf(one_m_alpha, 1e-8f));
    float c1 = one_m_alpha / sqrt_1ma;
    float sqa = sqrtf(alphaf);
    float sigma = 0.0f;
    if (t > 0) {
      float ap = 1.0f - sched[t - 1];
      sigma = sqrtf(fmaxf((1.0f - ap) / one_m_alpha * (1.0f - alphaf / ap), 0.0f));
    }
    uint32_t kt0, kt1; tf2x32(0u, 1u, 0u, (uint32_t)t, kt0, kt1);
    update_kernel<<<(nElem + 255) / 256, 256, 0, stream>>>(
        x, xbf, d0, d1, itf, a_amp, b_amp, ph, coh, c1, sqa, sigma,
        (t > 0) ? 1 : 0, kt0, kt1, nElem);
    coh *= decay;
  }

  uint32_t ku0, ku1; tf2x32(0u, 1u, 0u, 99999u, ku0, ku1);
  final_kernel<<<(nElem + 255) / 256, 256, 0, stream>>>(
      x, real, (float*)d_out, a_amp, b_amp, ku0, ku1, nElem);
}